// Round 1
// baseline (55.953 us; speedup 1.0000x reference)
//
#include <hip/hip_runtime.h>

#define N_KNOTS 4096
#define N_SEG (N_KNOTS - 1)
#define BLOCK 256

__device__ __forceinline__ float pchip_eval(float tq, const float* ys, const float* ds) {
    int idx = (int)tq;                       // t >= 0, truncation == floor
    idx = min(max(idx, 0), N_SEG - 1);
    float tn = tq - (float)idx;              // dx_seg == 1 exactly (x = arange)
    float y0 = ys[idx];
    float y1 = ys[idx + 1];
    float d0 = ds[idx];
    float d1 = ds[idx + 1];
    float t2 = tn * tn;
    float t3 = t2 * tn;
    float h00 = 2.0f * t3 - 3.0f * t2 + 1.0f;
    float h10 = t3 - 2.0f * t2 + tn;
    float h01 = 3.0f * t2 - 2.0f * t3;
    float h11 = t3 - t2;
    return h00 * y0 + h10 * d0 + h01 * y1 + h11 * d1;
}

__global__ __launch_bounds__(BLOCK) void pchip_kernel(
    const float* __restrict__ y,
    const float* __restrict__ t,
    float* __restrict__ out,
    int n_queries)
{
    __shared__ float ys[N_KNOTS];
    __shared__ float ds[N_KNOTS];

    // Stage y into LDS (16 KB), coalesced.
    for (int i = threadIdx.x; i < N_KNOTS; i += BLOCK)
        ys[i] = y[i];
    __syncthreads();

    // PCHIP derivatives on a uniform grid (dx0 = dx1 = 1 -> w1 = w2 = 3).
    // d[i] = (w1+w2)/(w1/s0 + w2/s1) if s0*s1 > 0 else 0; endpoints = one-sided slope.
    for (int i = threadIdx.x; i < N_KNOTS; i += BLOCK) {
        float dval;
        if (i == 0) {
            dval = ys[1] - ys[0];
        } else if (i == N_KNOTS - 1) {
            dval = ys[N_KNOTS - 1] - ys[N_KNOTS - 2];
        } else {
            float s0 = ys[i] - ys[i - 1];
            float s1 = ys[i + 1] - ys[i];
            dval = (s0 * s1 > 0.0f) ? (6.0f / (3.0f / s0 + 3.0f / s1)) : 0.0f;
        }
        ds[i] = dval;
    }
    __syncthreads();

    // Streaming phase: vectorized float4 grid-stride loop.
    const int n4 = n_queries >> 2;
    const float4* __restrict__ t4 = (const float4*)t;
    float4* __restrict__ o4 = (float4*)out;
    const int stride = gridDim.x * blockDim.x;

    for (int i = blockIdx.x * blockDim.x + threadIdx.x; i < n4; i += stride) {
        float4 tv = t4[i];
        float4 r;
        r.x = pchip_eval(tv.x, ys, ds);
        r.y = pchip_eval(tv.y, ys, ds);
        r.z = pchip_eval(tv.z, ys, ds);
        r.w = pchip_eval(tv.w, ys, ds);
        o4[i] = r;
    }

    // Scalar tail (n_queries % 4), defensive — 33554432 is divisible by 4.
    const int tail_start = n4 << 2;
    for (int i = tail_start + blockIdx.x * blockDim.x + threadIdx.x;
         i < n_queries; i += stride) {
        out[i] = pchip_eval(t[i], ys, ds);
    }
}

extern "C" void kernel_launch(void* const* d_in, const int* in_sizes, int n_in,
                              void* d_out, int out_size, void* d_ws, size_t ws_size,
                              hipStream_t stream) {
    // inputs: d_in[0] = x (4096 f32, arange), d_in[1] = y (4096 f32),
    //         d_in[2] = t (33554432 f32)
    const float* y = (const float*)d_in[1];
    const float* t = (const float*)d_in[2];
    float* out = (float*)d_out;
    const int n_queries = in_sizes[2];

    const int blocks = 2048;   // 33554432/4 elems / (2048*256) = 16 iters/thread
    pchip_kernel<<<blocks, BLOCK, 0, stream>>>(y, t, out, n_queries);
}

// Round 3
// 47.610 us; speedup vs baseline: 1.1752x; 1.1752x over previous
//
#include <hip/hip_runtime.h>

#define N_KNOTS 4096
#define N_SEG (N_KNOTS - 1)   // 4095 segments
#define BLOCK 1024

typedef float f32x4 __attribute__((ext_vector_type(4)));

// Per-segment cubic coefficients: val(tn) = a + tn*(b + tn*(c + tn*d)), tn in [0,1)
// a = y0, b = d0, c = 3(y1-y0) - 2 d0 - d1, d = 2(y0-y1) + d0 + d1
__global__ __launch_bounds__(BLOCK, 8) void pchip_kernel(
    const float* __restrict__ y,
    const float* __restrict__ t,
    float* __restrict__ out,
    int n_queries)
{
    __shared__ float4 coef[N_SEG];   // 4095 * 16 B = 65520 B

    // Build coefficient table. Each thread handles ~4 segments; y is 16 KB and
    // L2-resident, so the redundant per-block global reads are negligible.
    for (int i = threadIdx.x; i < N_SEG; i += BLOCK) {
        float y0 = y[i];
        float y1 = y[i + 1];
        float s0 = y1 - y0;                        // slope of this segment
        float d0, d1;
        if (i == 0) {
            d0 = s0;                               // left endpoint: one-sided slope
        } else {
            float sm = y0 - y[i - 1];              // previous slope
            d0 = (sm * s0 > 0.0f) ? (2.0f * sm * s0) / (sm + s0) : 0.0f;
        }
        if (i == N_SEG - 1) {
            d1 = s0;                               // right endpoint: one-sided slope
        } else {
            float sp = y[i + 2] - y1;              // next slope
            d1 = (s0 * sp > 0.0f) ? (2.0f * s0 * sp) / (s0 + sp) : 0.0f;
        }
        float a = y0;
        float b = d0;
        float c = 3.0f * (y1 - y0) - 2.0f * d0 - d1;
        float dd = 2.0f * (y0 - y1) + d0 + d1;
        coef[i] = make_float4(a, b, c, dd);
    }
    __syncthreads();

    // Streaming phase: float4 loads of t, one ds_read_b128 per query, Horner eval.
    const int n4 = n_queries >> 2;
    const float4* __restrict__ t4 = (const float4*)t;
    f32x4* __restrict__ o4 = (f32x4*)out;
    const int stride = gridDim.x * blockDim.x;

    for (int i = blockIdx.x * blockDim.x + threadIdx.x; i < n4; i += stride) {
        float4 tv = t4[i];
        f32x4 r;
        {
            int idx = min(max((int)tv.x, 0), N_SEG - 1);
            float tn = tv.x - (float)idx;
            float4 cf = coef[idx];
            r.x = fmaf(fmaf(fmaf(cf.w, tn, cf.z), tn, cf.y), tn, cf.x);
        }
        {
            int idx = min(max((int)tv.y, 0), N_SEG - 1);
            float tn = tv.y - (float)idx;
            float4 cf = coef[idx];
            r.y = fmaf(fmaf(fmaf(cf.w, tn, cf.z), tn, cf.y), tn, cf.x);
        }
        {
            int idx = min(max((int)tv.z, 0), N_SEG - 1);
            float tn = tv.z - (float)idx;
            float4 cf = coef[idx];
            r.z = fmaf(fmaf(fmaf(cf.w, tn, cf.z), tn, cf.y), tn, cf.x);
        }
        {
            int idx = min(max((int)tv.w, 0), N_SEG - 1);
            float tn = tv.w - (float)idx;
            float4 cf = coef[idx];
            r.w = fmaf(fmaf(fmaf(cf.w, tn, cf.z), tn, cf.y), tn, cf.x);
        }
        // Non-temporal store: out is write-once, keep t resident in L3 instead.
        __builtin_nontemporal_store(r, &o4[i]);
    }

    // Scalar tail (defensive; 33554432 % 4 == 0).
    const int tail_start = n4 << 2;
    for (int i = tail_start + blockIdx.x * blockDim.x + threadIdx.x;
         i < n_queries; i += stride) {
        float tq = t[i];
        int idx = min(max((int)tq, 0), N_SEG - 1);
        float tn = tq - (float)idx;
        float4 cf = coef[idx];
        out[i] = fmaf(fmaf(fmaf(cf.w, tn, cf.z), tn, cf.y), tn, cf.x);
    }
}

extern "C" void kernel_launch(void* const* d_in, const int* in_sizes, int n_in,
                              void* d_out, int out_size, void* d_ws, size_t ws_size,
                              hipStream_t stream) {
    // inputs: d_in[0] = x (4096 f32, arange — implicit), d_in[1] = y, d_in[2] = t
    const float* y = (const float*)d_in[1];
    const float* t = (const float*)d_in[2];
    float* out = (float*)d_out;
    const int n_queries = in_sizes[2];

    // 512 blocks x 1024 threads: 2 blocks/CU (64 KB LDS each), 32 waves/CU.
    const int blocks = 512;
    pchip_kernel<<<blocks, BLOCK, 0, stream>>>(y, t, out, n_queries);
}

// Round 4
// 47.285 us; speedup vs baseline: 1.1833x; 1.0069x over previous
//
#include <hip/hip_runtime.h>

#define N_KNOTS 4096
#define N_SEG (N_KNOTS - 1)   // 4095 segments
#define BLOCK 1024

typedef float f32x4 __attribute__((ext_vector_type(4)));

__device__ __forceinline__ float horner(float tq, const float4* coef) {
    int idx = min(max((int)tq, 0), N_SEG - 1);
    float tn = tq - (float)idx;
    float4 cf = coef[idx];
    return fmaf(fmaf(fmaf(cf.w, tn, cf.z), tn, cf.y), tn, cf.x);
}

// Per-segment cubic coefficients: val(tn) = a + tn*(b + tn*(c + tn*d)), tn in [0,1)
__global__ __launch_bounds__(BLOCK, 8) void pchip_kernel(
    const float* __restrict__ y,
    const float* __restrict__ t,
    float* __restrict__ out,
    int n_queries)
{
    __shared__ float4 coef[N_SEG];   // 4095 * 16 B = 65520 B

    // Build coefficient table (y is 16 KB, L2-resident; redundant per-block reads ok).
    for (int i = threadIdx.x; i < N_SEG; i += BLOCK) {
        float y0 = y[i];
        float y1 = y[i + 1];
        float s0 = y1 - y0;
        float d0, d1;
        if (i == 0) {
            d0 = s0;
        } else {
            float sm = y0 - y[i - 1];
            d0 = (sm * s0 > 0.0f) ? (2.0f * sm * s0) / (sm + s0) : 0.0f;
        }
        if (i == N_SEG - 1) {
            d1 = s0;
        } else {
            float sp = y[i + 2] - y1;
            d1 = (s0 * sp > 0.0f) ? (2.0f * s0 * sp) / (s0 + sp) : 0.0f;
        }
        coef[i] = make_float4(y0, d0,
                              3.0f * (y1 - y0) - 2.0f * d0 - d1,
                              2.0f * (y0 - y1) + d0 + d1);
    }
    __syncthreads();

    // Streaming phase: 2 independent float4 chains per iteration for MLP.
    const int n4 = n_queries >> 2;
    const float4* __restrict__ t4 = (const float4*)t;
    f32x4* __restrict__ o4 = (f32x4*)out;
    const int gsz = gridDim.x * blockDim.x;
    const int tid = blockIdx.x * blockDim.x + threadIdx.x;

    int i = tid;
    // Main unrolled-by-2 loop: slots i and i+gsz, stride 2*gsz.
    for (; i + gsz < n4; i += 2 * gsz) {
        float4 ta = t4[i];
        float4 tb = t4[i + gsz];
        f32x4 ra, rb;
        ra.x = horner(ta.x, coef);
        ra.y = horner(ta.y, coef);
        ra.z = horner(ta.z, coef);
        ra.w = horner(ta.w, coef);
        rb.x = horner(tb.x, coef);
        rb.y = horner(tb.y, coef);
        rb.z = horner(tb.z, coef);
        rb.w = horner(tb.w, coef);
        __builtin_nontemporal_store(ra, &o4[i]);
        __builtin_nontemporal_store(rb, &o4[i + gsz]);
    }
    // Remainder single-slot (when n4/gsz is odd).
    for (; i < n4; i += gsz) {
        float4 ta = t4[i];
        f32x4 ra;
        ra.x = horner(ta.x, coef);
        ra.y = horner(ta.y, coef);
        ra.z = horner(ta.z, coef);
        ra.w = horner(ta.w, coef);
        __builtin_nontemporal_store(ra, &o4[i]);
    }

    // Scalar tail (defensive; 33554432 % 4 == 0).
    const int tail_start = n4 << 2;
    for (int j = tail_start + tid; j < n_queries; j += gsz) {
        out[j] = horner(t[j], (const float4*)coef);
    }
}

extern "C" void kernel_launch(void* const* d_in, const int* in_sizes, int n_in,
                              void* d_out, int out_size, void* d_ws, size_t ws_size,
                              hipStream_t stream) {
    // inputs: d_in[0] = x (arange, implicit), d_in[1] = y, d_in[2] = t
    const float* y = (const float*)d_in[1];
    const float* t = (const float*)d_in[2];
    float* out = (float*)d_out;
    const int n_queries = in_sizes[2];

    // 512 blocks x 1024 threads: 2 blocks/CU (64 KB LDS each), 32 waves/CU.
    const int blocks = 512;
    pchip_kernel<<<blocks, BLOCK, 0, stream>>>(y, t, out, n_queries);
}

// Round 5
// 47.003 us; speedup vs baseline: 1.1904x; 1.0060x over previous
//
#include <hip/hip_runtime.h>

#define N_KNOTS 4096
#define N_SEG (N_KNOTS - 1)   // 4095 segments
#define BLOCK 1024

typedef float f32x4 __attribute__((ext_vector_type(4)));

__device__ __forceinline__ float horner(float tq, const float4* coef) {
    int idx = min(max((int)tq, 0), N_SEG - 1);
    float tn = tq - (float)idx;
    float4 cf = coef[idx];
    return fmaf(fmaf(fmaf(cf.w, tn, cf.z), tn, cf.y), tn, cf.x);
}

// Per-segment cubic coefficients: val(tn) = a + tn*(b + tn*(c + tn*d)), tn in [0,1)
__global__ __launch_bounds__(BLOCK, 8) void pchip_kernel(
    const float* __restrict__ y,
    const float* __restrict__ t,
    float* __restrict__ out,
    int n_queries)
{
    __shared__ float4 coef[N_SEG];   // 4095 * 16 B = 65520 B

    // Build coefficient table (y is 16 KB, L2-resident; one-time ~0.2 us).
    for (int i = threadIdx.x; i < N_SEG; i += BLOCK) {
        float y0 = y[i];
        float y1 = y[i + 1];
        float s0 = y1 - y0;
        float d0, d1;
        if (i == 0) {
            d0 = s0;
        } else {
            float sm = y0 - y[i - 1];
            d0 = (sm * s0 > 0.0f) ? (2.0f * sm * s0) / (sm + s0) : 0.0f;
        }
        if (i == N_SEG - 1) {
            d1 = s0;
        } else {
            float sp = y[i + 2] - y1;
            d1 = (s0 * sp > 0.0f) ? (2.0f * s0 * sp) / (s0 + sp) : 0.0f;
        }
        coef[i] = make_float4(y0, d0,
                              3.0f * (y1 - y0) - 2.0f * d0 - d1,
                              2.0f * (y0 - y1) + d0 + d1);
    }
    __syncthreads();

    // Streaming phase: software-pipelined grid-stride loop. The load of
    // iteration k+1 issues BEFORE iteration k's LDS-gather/FMA/store chain,
    // so the vmem pipe never idles behind the LDS chain.
    const int n4 = n_queries >> 2;
    const float4* __restrict__ t4 = (const float4*)t;
    f32x4* __restrict__ o4 = (f32x4*)out;
    const int gsz = gridDim.x * blockDim.x;
    const int tid = blockIdx.x * blockDim.x + threadIdx.x;

    int i = tid;
    if (i < n4) {
        float4 cur = t4[i];
        for (; i + gsz < n4; i += gsz) {
            float4 nxt = t4[i + gsz];     // prefetch next slot (independent)
            f32x4 r;
            r.x = horner(cur.x, coef);
            r.y = horner(cur.y, coef);
            r.z = horner(cur.z, coef);
            r.w = horner(cur.w, coef);
            __builtin_nontemporal_store(r, &o4[i]);
            cur = nxt;
        }
        // epilogue: last slot
        f32x4 r;
        r.x = horner(cur.x, coef);
        r.y = horner(cur.y, coef);
        r.z = horner(cur.z, coef);
        r.w = horner(cur.w, coef);
        __builtin_nontemporal_store(r, &o4[i]);
    }

    // Scalar tail (defensive; 33554432 % 4 == 0).
    const int tail_start = n4 << 2;
    for (int j = tail_start + tid; j < n_queries; j += gsz) {
        out[j] = horner(t[j], (const float4*)coef);
    }
}

extern "C" void kernel_launch(void* const* d_in, const int* in_sizes, int n_in,
                              void* d_out, int out_size, void* d_ws, size_t ws_size,
                              hipStream_t stream) {
    // inputs: d_in[0] = x (arange, implicit), d_in[1] = y, d_in[2] = t
    const float* y = (const float*)d_in[1];
    const float* t = (const float*)d_in[2];
    float* out = (float*)d_out;
    const int n_queries = in_sizes[2];

    // 512 blocks x 1024 threads: 2 blocks/CU (64 KB LDS each), 32 waves/CU.
    const int blocks = 512;
    pchip_kernel<<<blocks, BLOCK, 0, stream>>>(y, t, out, n_queries);
}